// Round 11
// baseline (311.399 us; speedup 1.0000x reference)
//
#include <hip/hip_runtime.h>

typedef _Float16 f16;
typedef __attribute__((ext_vector_type(8))) _Float16 f16x8;
typedef __attribute__((ext_vector_type(2))) __fp16 hf16x2;   // native type of cvt_pkrtz
typedef __attribute__((ext_vector_type(4))) float f32x4;

constexpr int C_ = 4, L_ = 1000, K_ = 64, NOUT = 986, NPOS = 16 * 986; // 15776
constexpr int TPB  = 256;                       // 4 waves
constexpr int MTB  = 128;                       // positions per block (32/wave)
constexpr int NBLK = (NPOS + MTB - 1) / MTB;    // 124
constexpr int AST  = 104;                       // row stride (f16): 208 B, 16B-aligned
constexpr int ACT_EL  = MTB * AST;              // 13312 f16 (single in-place act buffer)
// LDS: act 26624 + bias(fp32) 1920 + head(fp32) 256 = 28800 B
constexpr size_t SMEM_BYTES = (size_t)ACT_EL * 2 + 480 * 4 + 64 * 4;

// ws: per layer l, per k: 96-row stride x AST cols fp16 W^T (row=out e, col=in d), zero-padded.
constexpr size_t WOFF[5]  = {0, 638976, 1277952, 1916928, 2555904};
constexpr int    WROWS[5] = {80, 96, 96, 80, 64};   // ceil16(DO)
constexpr int    DIv[5]   = {60, 72, 86, 86, 71};
constexpr int    DOv[5]   = {72, 86, 86, 71, 59};

__device__ __forceinline__ float gelu_f(float x) {
    // tanh-form gelu as x*sigmoid(2z); validated R4/R9/R10 (absmax 3.9e-3)
    float x2 = x * x;
    float z  = x * __builtin_fmaf(0.0356774081f, x2, 0.7978845608f);
    float e  = __expf(-2.0f * z);
    return x * __builtin_amdgcn_rcpf(e + 1.0f);
}

// A = W^T fragments read DIRECTLY FROM GLOBAL (L2-resident: all 124 m-blocks of a k reuse the
// same ~87 KB of W). B = act rows from wave-private LDS. No weight staging, no barriers.
template<int KSTEPS, int MT>
__device__ __forceinline__ void layer_mm_g(const f16* __restrict__ actw,
                                           const f16* __restrict__ wsrc,
                                           f32x4 (&acc)[MT][2], int li, int q) {
#pragma unroll
    for (int mt = 0; mt < MT; mt++)
#pragma unroll
        for (int nt = 0; nt < 2; nt++) acc[mt][nt] = f32x4{0.f, 0.f, 0.f, 0.f};
#pragma unroll
    for (int ks = 0; ks < KSTEPS; ks++) {
        const int koff = ks * 32 + q * 8;
        f16x8 a[MT], b[2];
#pragma unroll
        for (int mt = 0; mt < MT; mt++)
            a[mt] = *(const f16x8*)(wsrc + (mt * 16 + li) * AST + koff);   // global_load_dwordx4
#pragma unroll
        for (int nt = 0; nt < 2; nt++)
            b[nt] = *(const f16x8*)(actw + (nt * 16 + li) * AST + koff);   // ds_read_b128
#pragma unroll
        for (int mt = 0; mt < MT; mt++)
#pragma unroll
            for (int nt = 0; nt < 2; nt++)
                acc[mt][nt] = __builtin_amdgcn_mfma_f32_16x16x32_f16(a[mt], b[nt], acc[mt][nt], 0, 0, 0);
    }
}

// C/D: col(n=pos)=lane&15, row(m=e)=(lane>>4)*4+r -> lane owns 4 consecutive features of one
// position: fp32 bias add + gelu + pkrtz + one ds_write_b64. In-place act update: rows are
// wave-private, so NO barrier between layers.
template<int MT>
__device__ __forceinline__ void epilogue(f32x4 (&acc)[MT][2], f16* __restrict__ actw,
                                         const float* __restrict__ bl, int li, int q) {
#pragma unroll
    for (int mt = 0; mt < MT; mt++) {
        const int eb = mt * 16 + q * 4;
        f32x4 bb = *(const f32x4*)(bl + eb);       // same addr across li: LDS broadcast
#pragma unroll
        for (int nt = 0; nt < 2; nt++) {
            union { hf16x2 h[2]; unsigned long long u; } pk;
            pk.h[0] = __builtin_amdgcn_cvt_pkrtz(gelu_f(acc[mt][nt][0] + bb[0]),
                                                 gelu_f(acc[mt][nt][1] + bb[1]));
            pk.h[1] = __builtin_amdgcn_cvt_pkrtz(gelu_f(acc[mt][nt][2] + bb[2]),
                                                 gelu_f(acc[mt][nt][3] + bb[3]));
            f16* dst = actw + (nt * 16 + li) * AST + eb;   // 8B aligned
            *(unsigned long long*)dst = pk.u;
        }
    }
}

// prep (R11 rewrite): per-layer template => compile-time DI/DO/RW: fully unrolled batched
// global loads (one waitcnt), magic-mul divisions, and LDS transpose buffer padded to
// stride 87 f16 (8-row read step = 348 dwords = 28 mod 32 -> <=4-way banks vs 13-way).
template<int L>
__device__ __forceinline__ void prep_one(const float* __restrict__ wsrc0, f16* __restrict__ ws,
                                         f16* __restrict__ wl, int k, int tid) {
    constexpr int DI = DIv[L], DO = DOv[L], RW = WROWS[L];
    const float* wsrc = wsrc0 + (size_t)k * DI * DO;
    constexpr int TOT = DI * DO;
    constexpr int NIT = (TOT + 255) / 256;
    float v[NIT];
#pragma unroll
    for (int it = 0; it < NIT; it++) {
        int i = tid + it * 256;
        v[it] = (i < TOT) ? wsrc[i] : 0.f;     // all loads in flight before first use
    }
#pragma unroll
    for (int it = 0; it < NIT; it++) {
        int i = tid + it * 256;
        if (i < TOT) {
            int d = i / DO, e = i - d * DO;    // constexpr DO -> magic mul
            wl[d * 87 + e] = (f16)v[it];       // consecutive e: conflict-free writes
        }
    }
    __syncthreads();
    f16* dst = ws + WOFF[L] + (size_t)k * 96 * AST;
    constexpr int CH = RW * 13;                // 13 f16x8 chunks per row
    constexpr int NIT2 = (CH + 255) / 256;
#pragma unroll
    for (int it = 0; it < NIT2; it++) {
        int c = tid + it * 256;
        if (c < CH) {
            int e = c / 13, db = (c - e * 13) * 8;
            f16x8 vv;
#pragma unroll
            for (int j = 0; j < 8; j++) {
                int d = db + j;
                vv[j] = (e < DO && d < DI) ? wl[d * 87 + e] : (f16)0.f;
            }
            *(f16x8*)(dst + (size_t)c * 8) = vv;   // lane-consecutive 16B: coalesced
        }
    }
}

__global__ __launch_bounds__(256) void prep_weights(
    const float* __restrict__ w0, const float* __restrict__ w1, const float* __restrict__ w2,
    const float* __restrict__ w3, const float* __restrict__ w4, f16* __restrict__ ws) {
    __shared__ f16 wl[86 * 87];                // 14964 B
    const int k = blockIdx.x, tid = threadIdx.x;
    switch (blockIdx.y) {
        case 0: prep_one<0>(w0, ws, wl, k, tid); break;
        case 1: prep_one<1>(w1, ws, wl, k, tid); break;
        case 2: prep_one<2>(w2, ws, wl, k, tid); break;
        case 3: prep_one<3>(w3, ws, wl, k, tid); break;
        default: prep_one<4>(w4, ws, wl, k, tid); break;
    }
}

__global__ __launch_bounds__(TPB, 4) void mlp_main(   // R10 verbatim (262 us validated)
    const float* __restrict__ x,
    const float* __restrict__ b0, const float* __restrict__ b1, const float* __restrict__ b2,
    const float* __restrict__ b3, const float* __restrict__ b4,
    const float* __restrict__ hw, const float* __restrict__ hb,
    const f16* __restrict__ ws, float* __restrict__ out) {
    extern __shared__ char smemraw[];
    f16*   act   = (f16*)smemraw;                 // [128 pos][AST]
    float* biasl = (float*)(act + ACT_EL);        // 5 layers x 96 padded biases, fp32
    float* headl = biasl + 480;                   // 64 padded head weights, fp32

    const int tid = threadIdx.x, k = blockIdx.x, mblk = blockIdx.y;
    const int wv = tid >> 6, lane = tid & 63, li = lane & 15, q = lane >> 4;
    const int base = mblk * MTB;
    f16* actw = act + (wv * 32) * AST;            // this wave's 32 position rows
    const f16* wk = ws + (size_t)k * 96 * AST;    // k's weight panel base (per-layer via WOFF)

    // biases (padded to 96, fp32) + head weights into LDS
    for (int i = tid; i < 480; i += TPB) {
        int l = i / 96, e = i - l * 96;
        const float* bg = (l == 0) ? b0 : (l == 1) ? b1 : (l == 2) ? b2 : (l == 3) ? b3 : b4;
        int DO = (l == 0) ? 72 : (l == 1) ? 86 : (l == 2) ? 86 : (l == 3) ? 71 : 59;
        biasl[i] = (e < DO) ? bg[k * DO + e] : 0.f;
    }
    if (tid < 64) headl[tid] = (tid < 59) ? hw[tid] : 0.f;

    // layer-0 activations: act[pos][d], d = c*15+j in 0..59, cols 60..63 zero (K-pad).
    {
        const int b0i = base / NOUT;
        const int thr = (b0i + 1) * NOUT;
        for (int i = tid; i < 64 * MTB; i += TPB) {
            int d = i >> 7, r = i & (MTB - 1);
            int p = base + r; if (p > NPOS - 1) p = NPOS - 1;
            int b = (p >= thr) ? b0i + 1 : b0i;
            int pos = p - b * NOUT;
            float v = 0.f;
            if (d < 60) { int c = d / 15, j = d - c * 15; v = x[(size_t)(b * C_ + c) * L_ + pos + j]; }
            act[r * AST + d] = (f16)v;
        }
    }
    // act cols 80..95: read by K=96 loops (x zero W cols) but never written by MT=5 epilogues.
    // Zero all 16 cols once (two 16B stores per row; R9-validated).
    for (int i = tid; i < MTB * 2; i += TPB) {
        int r = i >> 1, cc = (i & 1) << 3;
        *(f16x8*)(act + r * AST + 80 + cc) = f16x8{0,0,0,0,0,0,0,0};
    }
    const float hb0 = hb[0];
    __syncthreads();     // the ONLY barrier: act gather is cross-wave interleaved

    f32x4 acc[6][2];
    f32x4 (&acc5)[5][2] = reinterpret_cast<f32x4 (&)[5][2]>(acc);

    layer_mm_g<2, 5>(actw, wk + WOFF[0], acc5, li, q);    // L0: K=64, DO=72
    epilogue<5>(acc5, actw, biasl + 0 * 96, li, q);
    layer_mm_g<3, 6>(actw, wk + WOFF[1], acc, li, q);     // L1: K=96(72 real), DO=86
    epilogue<6>(acc, actw, biasl + 1 * 96, li, q);
    layer_mm_g<3, 6>(actw, wk + WOFF[2], acc, li, q);     // L2: K=96(86), DO=86
    epilogue<6>(acc, actw, biasl + 2 * 96, li, q);
    layer_mm_g<3, 5>(actw, wk + WOFF[3], acc5, li, q);    // L3: K=96(86), DO=71
    epilogue<5>(acc5, actw, biasl + 3 * 96, li, q);
    // after L3: cols 80..95 hold stale L2 outputs — harmless: W4^T cols d>=71 are zero.

    // L4 + fused head: e 0..63 (4 m-tiles), fp32 gelu dot hw, butterfly over q
    f32x4 acc4[4][2];
    layer_mm_g<3, 4>(actw, wk + WOFF[4], acc4, li, q);
    float sum[2] = {0.f, 0.f};
#pragma unroll
    for (int mt = 0; mt < 4; mt++) {
        const int eb = mt * 16 + q * 4;
        f32x4 bb = *(const f32x4*)(biasl + 4 * 96 + eb);
        f32x4 hh = *(const f32x4*)(headl + eb);
#pragma unroll
        for (int nt = 0; nt < 2; nt++) {
#pragma unroll
            for (int r = 0; r < 4; r++)
                sum[nt] += gelu_f(acc4[mt][nt][r] + bb[r]) * hh[r];
        }
    }
#pragma unroll
    for (int nt = 0; nt < 2; nt++) {
        float s = sum[nt];
        s += __shfl_xor(s, 16);
        s += __shfl_xor(s, 32);
        s += hb0;
        if (lane < 16) {
            int p = base + wv * 32 + nt * 16 + lane;
            if (p < NPOS) {
                int b = p / NOUT, pos = p - b * NOUT;
                out[((size_t)(b * K_ + k)) * NOUT + pos] = s;
            }
        }
    }
}

extern "C" void kernel_launch(void* const* d_in, const int* in_sizes, int n_in,
                              void* d_out, int out_size, void* d_ws, size_t ws_size,
                              hipStream_t stream) {
    const float* x  = (const float*)d_in[0];
    const float* w0 = (const float*)d_in[1];  const float* b0 = (const float*)d_in[2];
    const float* w1 = (const float*)d_in[3];  const float* b1 = (const float*)d_in[4];
    const float* w2 = (const float*)d_in[5];  const float* b2 = (const float*)d_in[6];
    const float* w3 = (const float*)d_in[7];  const float* b3 = (const float*)d_in[8];
    const float* w4 = (const float*)d_in[9];  const float* b4 = (const float*)d_in[10];
    const float* hw = (const float*)d_in[11]; const float* hb = (const float*)d_in[12];
    float* out = (float*)d_out;
    f16* ws = (f16*)d_ws;   // 5.96 MB

    (void)hipFuncSetAttribute((const void*)mlp_main,
                              hipFuncAttributeMaxDynamicSharedMemorySize, (int)SMEM_BYTES);

    prep_weights<<<dim3(K_, 5), 256, 0, stream>>>(w0, w1, w2, w3, w4, ws);
    // grid x=k: linear id = k + 64*m -> XCD = k%8: all m-blocks of a k share one XCD's L2
    mlp_main<<<dim3(K_, NBLK), TPB, SMEM_BYTES, stream>>>(x, b0, b1, b2, b3, b4, hw, hb, ws, out);
}

// Round 12
// 290.617 us; speedup vs baseline: 1.0715x; 1.0715x over previous
//
#include <hip/hip_runtime.h>

typedef _Float16 f16;
typedef __attribute__((ext_vector_type(8))) _Float16 f16x8;
typedef __attribute__((ext_vector_type(2))) __fp16 hf16x2;   // native type of cvt_pkrtz
typedef __attribute__((ext_vector_type(4))) float f32x4;

constexpr int C_ = 4, L_ = 1000, K_ = 64, NOUT = 986, NPOS = 16 * 986; // 15776
constexpr int TPB  = 256;                       // 4 waves
constexpr int MTB  = 128;                       // positions per block (32/wave)
constexpr int NBLK = (NPOS + MTB - 1) / MTB;    // 124
constexpr int AST  = 104;                       // row stride (f16): 208 B, 16B-aligned
constexpr int ACT_EL  = MTB * AST;              // 13312 f16 (single in-place act buffer)
// LDS: act 26624 + bias(fp32) 1920 + head(fp32) 256 = 28800 B
constexpr size_t SMEM_BYTES = (size_t)ACT_EL * 2 + 480 * 4 + 64 * 4;

// ws: per layer l, per k: 96-row stride x AST cols fp16 W^T (row=out e, col=in d), zero-padded.
constexpr size_t WOFF[5]  = {0, 638976, 1277952, 1916928, 2555904};
constexpr int    WROWS[5] = {80, 96, 96, 80, 64};   // ceil16(DO)
constexpr int    DIv[5]   = {60, 72, 86, 86, 71};
constexpr int    DOv[5]   = {72, 86, 86, 71, 59};

__device__ __forceinline__ float gelu_f(float x) {
    // tanh-form gelu as x*sigmoid(2z); validated R4/R9/R10 (absmax 3.9e-3)
    float x2 = x * x;
    float z  = x * __builtin_fmaf(0.0356774081f, x2, 0.7978845608f);
    float e  = __expf(-2.0f * z);
    return x * __builtin_amdgcn_rcpf(e + 1.0f);
}

// Prefetch ks=0 A-fragments of a layer into registers (24 VGPRs). Issued during the PREVIOUS
// layer's epilogue (~1300 cyc of gelu) so the L2 latency is fully hidden at layer start.
template<int MT>
__device__ __forceinline__ void pre_a(const f16* __restrict__ wsrc, f16x8 (&ap)[6],
                                      int li, int q) {
#pragma unroll
    for (int mt = 0; mt < MT; mt++)
        ap[mt] = *(const f16x8*)(wsrc + (mt * 16 + li) * AST + q * 8);
}

// A = W^T from global (L2-resident; ks=0 from prefetched regs). B = act rows from wave-private
// LDS. No weight staging in LDS, no inter-layer barriers.
template<int KSTEPS, int MT>
__device__ __forceinline__ void layer_mm_p(const f16* __restrict__ actw,
                                           const f16* __restrict__ wsrc,
                                           const f16x8 (&ap)[6],
                                           f32x4 (&acc)[MT][2], int li, int q) {
#pragma unroll
    for (int mt = 0; mt < MT; mt++)
#pragma unroll
        for (int nt = 0; nt < 2; nt++) acc[mt][nt] = f32x4{0.f, 0.f, 0.f, 0.f};
#pragma unroll
    for (int ks = 0; ks < KSTEPS; ks++) {
        const int koff = ks * 32 + q * 8;
        f16x8 a[MT], b[2];
#pragma unroll
        for (int mt = 0; mt < MT; mt++)
            a[mt] = (ks == 0) ? ap[mt]
                              : *(const f16x8*)(wsrc + (mt * 16 + li) * AST + koff);
#pragma unroll
        for (int nt = 0; nt < 2; nt++)
            b[nt] = *(const f16x8*)(actw + (nt * 16 + li) * AST + koff);   // ds_read_b128
#pragma unroll
        for (int mt = 0; mt < MT; mt++)
#pragma unroll
            for (int nt = 0; nt < 2; nt++)
                acc[mt][nt] = __builtin_amdgcn_mfma_f32_16x16x32_f16(a[mt], b[nt], acc[mt][nt], 0, 0, 0);
    }
}

// C/D: col(n=pos)=lane&15, row(m=e)=(lane>>4)*4+r -> lane owns 4 consecutive features of one
// position: fp32 bias add + gelu + pkrtz + one ds_write_b64. In-place act update: rows are
// wave-private, so NO barrier between layers.
template<int MT>
__device__ __forceinline__ void epilogue(f32x4 (&acc)[MT][2], f16* __restrict__ actw,
                                         const float* __restrict__ bl, int li, int q) {
#pragma unroll
    for (int mt = 0; mt < MT; mt++) {
        const int eb = mt * 16 + q * 4;
        f32x4 bb = *(const f32x4*)(bl + eb);       // same addr across li: LDS broadcast
#pragma unroll
        for (int nt = 0; nt < 2; nt++) {
            union { hf16x2 h[2]; unsigned long long u; } pk;
            pk.h[0] = __builtin_amdgcn_cvt_pkrtz(gelu_f(acc[mt][nt][0] + bb[0]),
                                                 gelu_f(acc[mt][nt][1] + bb[1]));
            pk.h[1] = __builtin_amdgcn_cvt_pkrtz(gelu_f(acc[mt][nt][2] + bb[2]),
                                                 gelu_f(acc[mt][nt][3] + bb[3]));
            f16* dst = actw + (nt * 16 + li) * AST + eb;   // 8B aligned
            *(unsigned long long*)dst = pk.u;
        }
    }
}

// prep (R11 form): per-layer template, fully unrolled, padded LDS transpose.
template<int L>
__device__ __forceinline__ void prep_one(const float* __restrict__ wsrc0, f16* __restrict__ ws,
                                         f16* __restrict__ wl, int k, int tid) {
    constexpr int DI = DIv[L], DO = DOv[L], RW = WROWS[L];
    const float* wsrc = wsrc0 + (size_t)k * DI * DO;
    constexpr int TOT = DI * DO;
    constexpr int NIT = (TOT + 255) / 256;
    float v[NIT];
#pragma unroll
    for (int it = 0; it < NIT; it++) {
        int i = tid + it * 256;
        v[it] = (i < TOT) ? wsrc[i] : 0.f;
    }
#pragma unroll
    for (int it = 0; it < NIT; it++) {
        int i = tid + it * 256;
        if (i < TOT) {
            int d = i / DO, e = i - d * DO;
            wl[d * 87 + e] = (f16)v[it];
        }
    }
    __syncthreads();
    f16* dst = ws + WOFF[L] + (size_t)k * 96 * AST;
    constexpr int CH = RW * 13;
    constexpr int NIT2 = (CH + 255) / 256;
#pragma unroll
    for (int it = 0; it < NIT2; it++) {
        int c = tid + it * 256;
        if (c < CH) {
            int e = c / 13, db = (c - e * 13) * 8;
            f16x8 vv;
#pragma unroll
            for (int j = 0; j < 8; j++) {
                int d = db + j;
                vv[j] = (e < DO && d < DI) ? wl[d * 87 + e] : (f16)0.f;
            }
            *(f16x8*)(dst + (size_t)c * 8) = vv;
        }
    }
}

__global__ __launch_bounds__(256) void prep_weights(
    const float* __restrict__ w0, const float* __restrict__ w1, const float* __restrict__ w2,
    const float* __restrict__ w3, const float* __restrict__ w4, f16* __restrict__ ws) {
    __shared__ f16 wl[86 * 87];
    const int k = blockIdx.x, tid = threadIdx.x;
    switch (blockIdx.y) {
        case 0: prep_one<0>(w0, ws, wl, k, tid); break;
        case 1: prep_one<1>(w1, ws, wl, k, tid); break;
        case 2: prep_one<2>(w2, ws, wl, k, tid); break;
        case 3: prep_one<3>(w3, ws, wl, k, tid); break;
        default: prep_one<4>(w4, ws, wl, k, tid); break;
    }
}

__global__ __launch_bounds__(TPB, 4) void mlp_main(
    const float* __restrict__ x,
    const float* __restrict__ b0, const float* __restrict__ b1, const float* __restrict__ b2,
    const float* __restrict__ b3, const float* __restrict__ b4,
    const float* __restrict__ hw, const float* __restrict__ hb,
    const f16* __restrict__ ws, float* __restrict__ out) {
    extern __shared__ char smemraw[];
    f16*   act   = (f16*)smemraw;                 // [128 pos][AST]
    float* biasl = (float*)(act + ACT_EL);        // 5 layers x 96 padded biases, fp32
    float* headl = biasl + 480;                   // 64 padded head weights, fp32

    const int tid = threadIdx.x, k = blockIdx.x, mblk = blockIdx.y;
    const int wv = tid >> 6, lane = tid & 63, li = lane & 15, q = lane >> 4;
    const int base = mblk * MTB;
    f16* actw = act + (wv * 32) * AST;            // this wave's 32 position rows
    const f16* wk = ws + (size_t)k * 96 * AST;    // k's weight panel base (per-layer via WOFF)

    f16x8 ap[6];
    pre_a<5>(wk + WOFF[0], ap, li, q);            // L0 ks=0 frags hide under the gather

    // biases (padded to 96, fp32) + head weights into LDS
    for (int i = tid; i < 480; i += TPB) {
        int l = i / 96, e = i - l * 96;
        const float* bg = (l == 0) ? b0 : (l == 1) ? b1 : (l == 2) ? b2 : (l == 3) ? b3 : b4;
        int DO = (l == 0) ? 72 : (l == 1) ? 86 : (l == 2) ? 86 : (l == 3) ? 71 : 59;
        biasl[i] = (e < DO) ? bg[k * DO + e] : 0.f;
    }
    if (tid < 64) headl[tid] = (tid < 59) ? hw[tid] : 0.f;

    // layer-0 activations: act[pos][d], d = c*15+j in 0..59, cols 60..63 zero (K-pad).
    {
        const int b0i = base / NOUT;
        const int thr = (b0i + 1) * NOUT;
        for (int i = tid; i < 64 * MTB; i += TPB) {
            int d = i >> 7, r = i & (MTB - 1);
            int p = base + r; if (p > NPOS - 1) p = NPOS - 1;
            int b = (p >= thr) ? b0i + 1 : b0i;
            int pos = p - b * NOUT;
            float v = 0.f;
            if (d < 60) { int c = d / 15, j = d - c * 15; v = x[(size_t)(b * C_ + c) * L_ + pos + j]; }
            act[r * AST + d] = (f16)v;
        }
    }
    // act cols 80..95: read by K=96 loops (x zero W cols) but never written by MT=5 epilogues.
    // Zero all 16 cols once (two 16B stores per row; R9-validated).
    for (int i = tid; i < MTB * 2; i += TPB) {
        int r = i >> 1, cc = (i & 1) << 3;
        *(f16x8*)(act + r * AST + 80 + cc) = f16x8{0,0,0,0,0,0,0,0};
    }
    const float hb0 = hb[0];
    __syncthreads();     // the ONLY barrier

    f32x4 acc[6][2];
    f32x4 (&acc5)[5][2] = reinterpret_cast<f32x4 (&)[5][2]>(acc);

    layer_mm_p<2, 5>(actw, wk + WOFF[0], ap, acc5, li, q);    // L0: K=64, DO=72
    pre_a<6>(wk + WOFF[1], ap, li, q);                        // W1 ks=0 under L0 epilogue
    epilogue<5>(acc5, actw, biasl + 0 * 96, li, q);
    layer_mm_p<3, 6>(actw, wk + WOFF[1], ap, acc, li, q);     // L1: K=96(72 real), DO=86
    pre_a<6>(wk + WOFF[2], ap, li, q);
    epilogue<6>(acc, actw, biasl + 1 * 96, li, q);
    layer_mm_p<3, 6>(actw, wk + WOFF[2], ap, acc, li, q);     // L2: K=96(86), DO=86
    pre_a<5>(wk + WOFF[3], ap, li, q);
    epilogue<6>(acc, actw, biasl + 2 * 96, li, q);
    layer_mm_p<3, 5>(actw, wk + WOFF[3], ap, acc5, li, q);    // L3: K=96(86), DO=71
    pre_a<4>(wk + WOFF[4], ap, li, q);
    epilogue<5>(acc5, actw, biasl + 3 * 96, li, q);
    // after L3: cols 80..95 hold stale L2 outputs — harmless: W4^T cols d>=71 are zero.

    // L4 + fused head: e 0..63 (4 m-tiles), fp32 gelu dot hw, butterfly over q
    f32x4 acc4[4][2];
    layer_mm_p<3, 4>(actw, wk + WOFF[4], ap, acc4, li, q);
    float sum[2] = {0.f, 0.f};
#pragma unroll
    for (int mt = 0; mt < 4; mt++) {
        const int eb = mt * 16 + q * 4;
        f32x4 bb = *(const f32x4*)(biasl + 4 * 96 + eb);
        f32x4 hh = *(const f32x4*)(headl + eb);
#pragma unroll
        for (int nt = 0; nt < 2; nt++) {
#pragma unroll
            for (int r = 0; r < 4; r++)
                sum[nt] += gelu_f(acc4[mt][nt][r] + bb[r]) * hh[r];
        }
    }
#pragma unroll
    for (int nt = 0; nt < 2; nt++) {
        float s = sum[nt];
        s += __shfl_xor(s, 16);
        s += __shfl_xor(s, 32);
        s += hb0;
        if (lane < 16) {
            int p = base + wv * 32 + nt * 16 + lane;
            if (p < NPOS) {
                int b = p / NOUT, pos = p - b * NOUT;
                out[((size_t)(b * K_ + k)) * NOUT + pos] = s;
            }
        }
    }
}

extern "C" void kernel_launch(void* const* d_in, const int* in_sizes, int n_in,
                              void* d_out, int out_size, void* d_ws, size_t ws_size,
                              hipStream_t stream) {
    const float* x  = (const float*)d_in[0];
    const float* w0 = (const float*)d_in[1];  const float* b0 = (const float*)d_in[2];
    const float* w1 = (const float*)d_in[3];  const float* b1 = (const float*)d_in[4];
    const float* w2 = (const float*)d_in[5];  const float* b2 = (const float*)d_in[6];
    const float* w3 = (const float*)d_in[7];  const float* b3 = (const float*)d_in[8];
    const float* w4 = (const float*)d_in[9];  const float* b4 = (const float*)d_in[10];
    const float* hw = (const float*)d_in[11]; const float* hb = (const float*)d_in[12];
    float* out = (float*)d_out;
    f16* ws = (f16*)d_ws;   // 5.96 MB

    (void)hipFuncSetAttribute((const void*)mlp_main,
                              hipFuncAttributeMaxDynamicSharedMemorySize, (int)SMEM_BYTES);

    prep_weights<<<dim3(K_, 5), 256, 0, stream>>>(w0, w1, w2, w3, w4, ws);
    // grid x=k: linear id = k + 64*m -> XCD = k%8: all m-blocks of a k share one XCD's L2
    mlp_main<<<dim3(K_, NBLK), TPB, SMEM_BYTES, stream>>>(x, b0, b1, b2, b3, b4, hw, hb, ws, out);
}